// Round 2
// baseline (602.045 us; speedup 1.0000x reference)
//
#include <hip/hip_runtime.h>
#include <hip/hip_bf16.h>

#define N_TOK   4096
#define DM      1024
#define DF      2048
#define NEXP    8
#define NPAIR   (N_TOK * 2)
#define BM      128
#define BN      128
#define BK      32
#define LDK     40      // BK + 8 pad; 80B row stride (16B-aligned, 2-way bank alias = free)

typedef __attribute__((ext_vector_type(8))) short bf16x8;
typedef __attribute__((ext_vector_type(4))) float f32x4;

// fp32 -> bf16 round-to-nearest-even, pure bit manipulation (no hip_bf16 class types)
__device__ __forceinline__ unsigned short to_bf16(float f) {
    unsigned u = __builtin_bit_cast(unsigned, f);
    unsigned r = (u + 0x7FFFu + ((u >> 16) & 1u)) >> 16;
    return (unsigned short)r;
}
__device__ __forceinline__ unsigned pk_bf16(float a, float b) {
    return (unsigned)to_bf16(a) | ((unsigned)to_bf16(b) << 16);
}

// ---------------- sort pairs by expert ----------------
// meta layout (ints): [0..8) counts, [8..16) cursors, [16..25) rowOff, [25..34) mtOff, [34] totalMT
__global__ void k_count(const int* __restrict__ eidx, int* __restrict__ meta) {
    int i = blockIdx.x * 256 + threadIdx.x;
    if (i < NPAIR) atomicAdd(&meta[eidx[i] & 7], 1);
}
__global__ void k_scan(int* __restrict__ meta) {
    if (threadIdx.x == 0) {
        int off = 0, mt = 0;
        for (int e = 0; e < NEXP; ++e) {
            meta[16 + e] = off; meta[25 + e] = mt;
            int c = meta[e];
            off += c; mt += (c + BM - 1) / BM;
        }
        meta[16 + NEXP] = off; meta[25 + NEXP] = mt; meta[34] = mt;
    }
}
__global__ void k_scatter(const int* __restrict__ eidx, int* __restrict__ meta,
                          int* __restrict__ rows) {
    int i = blockIdx.x * 256 + threadIdx.x;
    if (i < NPAIR) {
        int e = eidx[i] & 7;
        int p = meta[16 + e] + atomicAdd(&meta[8 + e], 1);
        rows[p] = i;   // pair id: token = i>>1, slot = i&1
    }
}

// ---------------- GEMM1: H = silu(X W1) * (X W2), per-expert segments ----------------
__global__ __launch_bounds__(256, 2)
void k_gemm1(const float* __restrict__ x,
             const float* __restrict__ w1,
             const float* __restrict__ w2,
             const int*   __restrict__ meta,
             const int*   __restrict__ rows,
             unsigned short* __restrict__ H)
{
    __shared__ unsigned short As[BM][LDK];
    __shared__ unsigned short B1s[BN][LDK];
    __shared__ unsigned short B2s[BN][LDK];
    __shared__ int s_tok[BM];

    const int mt = blockIdx.y;
    if (mt >= meta[34]) return;
    int e = 0;
    #pragma unroll
    for (int i = 0; i < NEXP - 1; ++i) if (mt >= meta[25 + i + 1]) e = i + 1;
    const int rowEnd = meta[16 + e + 1];
    const int row0   = meta[16 + e] + (mt - meta[25 + e]) * BM;
    const int f0     = blockIdx.x * BN;
    const int tid    = threadIdx.x;

    if (tid < BM) {
        int gr = row0 + tid;
        s_tok[tid] = (gr < rowEnd) ? (rows[gr] >> 1) : -1;
    }
    __syncthreads();

    // A staging map: 2 threads/row, 16 consecutive k each
    const int ar = tid >> 1;
    const int ah = (tid & 1) * 16;
    const int a_tok = s_tok[ar];
    const float* a_src = x + (size_t)(a_tok < 0 ? 0 : a_tok) * DM + ah;

    // B staging map: thread owns column n=bn_, k-range [bk_, bk_+16)
    const int bn_ = tid & 127;
    const int bk_ = (tid >> 7) * 16;
    const float* b1_src = w1 + (size_t)e * DM * DF + (size_t)bk_ * DF + f0 + bn_;
    const float* b2_src = w2 + (size_t)e * DM * DF + (size_t)bk_ * DF + f0 + bn_;

    f32x4 accg[4][4], accv[4][4];
    #pragma unroll
    for (int i = 0; i < 4; ++i)
        #pragma unroll
        for (int j = 0; j < 4; ++j) { accg[i][j] = (f32x4)0.f; accv[i][j] = (f32x4)0.f; }

    const int lane = tid & 63;
    const int wave = tid >> 6;
    const int wm = (wave >> 1) * 64;
    const int wn = (wave & 1) * 64;
    const int am = lane & 15;
    const int ak = (lane >> 4) * 8;

    for (int k0 = 0; k0 < DM; k0 += BK) {
        { // stage A (gathered x rows, fp32 -> bf16)
            const float* p = a_src + k0;
            #pragma unroll
            for (int jj = 0; jj < 4; ++jj) {
                float4 v;
                if (a_tok < 0) { v.x = v.y = v.z = v.w = 0.f; }
                else           { v = *(const float4*)(p + jj * 4); }
                uint2 w;
                w.x = pk_bf16(v.x, v.y);
                w.y = pk_bf16(v.z, v.w);
                *(uint2*)&As[ar][ah + jj * 4] = w;
            }
        }
        { // stage B1/B2: fp32 [k][f] -> bf16 LDS [f][k] (transposed)
            const float* p1 = b1_src + (size_t)k0 * DF;
            const float* p2 = b2_src + (size_t)k0 * DF;
            #pragma unroll
            for (int c = 0; c < 2; ++c) {
                float v[8];
                #pragma unroll
                for (int j = 0; j < 8; ++j) v[j] = p1[(size_t)(c * 8 + j) * DF];
                uint4 w;
                w.x = pk_bf16(v[0], v[1]); w.y = pk_bf16(v[2], v[3]);
                w.z = pk_bf16(v[4], v[5]); w.w = pk_bf16(v[6], v[7]);
                *(uint4*)&B1s[bn_][bk_ + c * 8] = w;
            }
            #pragma unroll
            for (int c = 0; c < 2; ++c) {
                float v[8];
                #pragma unroll
                for (int j = 0; j < 8; ++j) v[j] = p2[(size_t)(c * 8 + j) * DF];
                uint4 w;
                w.x = pk_bf16(v[0], v[1]); w.y = pk_bf16(v[2], v[3]);
                w.z = pk_bf16(v[4], v[5]); w.w = pk_bf16(v[6], v[7]);
                *(uint4*)&B2s[bn_][bk_ + c * 8] = w;
            }
        }
        __syncthreads();

        bf16x8 a[4], b1[4], b2[4];
        #pragma unroll
        for (int mi = 0; mi < 4; ++mi) a[mi] = *(const bf16x8*)&As[wm + mi * 16 + am][ak];
        #pragma unroll
        for (int ni = 0; ni < 4; ++ni) {
            b1[ni] = *(const bf16x8*)&B1s[wn + ni * 16 + am][ak];
            b2[ni] = *(const bf16x8*)&B2s[wn + ni * 16 + am][ak];
        }
        #pragma unroll
        for (int mi = 0; mi < 4; ++mi)
            #pragma unroll
            for (int ni = 0; ni < 4; ++ni) {
                accg[mi][ni] = __builtin_amdgcn_mfma_f32_16x16x32_bf16(a[mi], b1[ni], accg[mi][ni], 0, 0, 0);
                accv[mi][ni] = __builtin_amdgcn_mfma_f32_16x16x32_bf16(a[mi], b2[ni], accv[mi][ni], 0, 0, 0);
            }
        __syncthreads();
    }

    // epilogue: h = silu(g)*v -> H[pos][f] bf16.  C/D layout: col=lane&15, row=(lane>>4)*4+reg
    const int cn = lane & 15;
    const int cq = (lane >> 4) * 4;
    #pragma unroll
    for (int mi = 0; mi < 4; ++mi) {
        #pragma unroll
        for (int r = 0; r < 4; ++r) {
            const int row = wm + mi * 16 + cq + r;
            const int gr  = row0 + row;
            if (gr < rowEnd) {
                unsigned short* dst = H + (size_t)gr * DF + f0 + wn;
                #pragma unroll
                for (int ni = 0; ni < 4; ++ni) {
                    float g = accg[mi][ni][r];
                    float v = accv[mi][ni][r];
                    float h = (g * v) / (1.f + __expf(-g));
                    dst[ni * 16 + cn] = to_bf16(h);
                }
            }
        }
    }
}

// ---------------- GEMM2: out[tok] += w * (H @ W3), per-expert segments ----------------
__global__ __launch_bounds__(256, 2)
void k_gemm2(const unsigned short* __restrict__ H,
             const float* __restrict__ w3,
             const int*   __restrict__ meta,
             const int*   __restrict__ rows,
             const float* __restrict__ ew,
             float* __restrict__ out)
{
    __shared__ unsigned short As[BM][LDK];
    __shared__ unsigned short Bs[BN][LDK];
    __shared__ int   s_tok[BM];
    __shared__ float s_w[BM];

    const int mt = blockIdx.y;
    if (mt >= meta[34]) return;
    int e = 0;
    #pragma unroll
    for (int i = 0; i < NEXP - 1; ++i) if (mt >= meta[25 + i + 1]) e = i + 1;
    const int rowEnd = meta[16 + e + 1];
    const int row0   = meta[16 + e] + (mt - meta[25 + e]) * BM;
    const int d0     = blockIdx.x * BN;
    const int tid    = threadIdx.x;

    if (tid < BM) {
        int gr = row0 + tid;
        if (gr < rowEnd) { int pr = rows[gr]; s_tok[tid] = pr >> 1; s_w[tid] = ew[pr]; }
        else             { s_tok[tid] = 0;    s_w[tid] = 0.f; }
    }
    __syncthreads();

    const int ar = tid >> 1;
    const int ah = (tid & 1) * 16;
    int a_row = row0 + ar; if (a_row >= NPAIR) a_row = NPAIR - 1;
    const unsigned short* a_src = H + (size_t)a_row * DF + ah;

    const int bn_ = tid & 127;
    const int bk_ = (tid >> 7) * 16;
    const float* b_src = w3 + (size_t)e * DF * DM + (size_t)bk_ * DM + d0 + bn_;

    f32x4 acc[4][4];
    #pragma unroll
    for (int i = 0; i < 4; ++i)
        #pragma unroll
        for (int j = 0; j < 4; ++j) acc[i][j] = (f32x4)0.f;

    const int lane = tid & 63;
    const int wave = tid >> 6;
    const int wm = (wave >> 1) * 64;
    const int wn = (wave & 1) * 64;
    const int am = lane & 15;
    const int ak = (lane >> 4) * 8;

    for (int k0 = 0; k0 < DF; k0 += BK) {
        // A: already bf16, rows contiguous (sorted) — straight 16B copies
        *(uint4*)&As[ar][ah]     = *(const uint4*)(a_src + k0);
        *(uint4*)&As[ar][ah + 8] = *(const uint4*)(a_src + k0 + 8);
        { // B: w3 fp32 [k][d] -> bf16 LDS [d][k]
            const float* p = b_src + (size_t)k0 * DM;
            #pragma unroll
            for (int c = 0; c < 2; ++c) {
                float v[8];
                #pragma unroll
                for (int j = 0; j < 8; ++j) v[j] = p[(size_t)(c * 8 + j) * DM];
                uint4 w;
                w.x = pk_bf16(v[0], v[1]); w.y = pk_bf16(v[2], v[3]);
                w.z = pk_bf16(v[4], v[5]); w.w = pk_bf16(v[6], v[7]);
                *(uint4*)&Bs[bn_][bk_ + c * 8] = w;
            }
        }
        __syncthreads();

        bf16x8 a[4], b[4];
        #pragma unroll
        for (int mi = 0; mi < 4; ++mi) a[mi] = *(const bf16x8*)&As[wm + mi * 16 + am][ak];
        #pragma unroll
        for (int ni = 0; ni < 4; ++ni) b[ni] = *(const bf16x8*)&Bs[wn + ni * 16 + am][ak];
        #pragma unroll
        for (int mi = 0; mi < 4; ++mi)
            #pragma unroll
            for (int ni = 0; ni < 4; ++ni)
                acc[mi][ni] = __builtin_amdgcn_mfma_f32_16x16x32_bf16(a[mi], b[ni], acc[mi][ni], 0, 0, 0);
        __syncthreads();
    }

    const int cn = lane & 15;
    const int cq = (lane >> 4) * 4;
    #pragma unroll
    for (int mi = 0; mi < 4; ++mi) {
        #pragma unroll
        for (int r = 0; r < 4; ++r) {
            const int row = wm + mi * 16 + cq + r;
            const int gr  = row0 + row;
            if (gr < rowEnd) {
                const int   tok = s_tok[row];
                const float wgt = s_w[row];
                float* dst = out + (size_t)tok * DM + d0 + wn;
                #pragma unroll
                for (int ni = 0; ni < 4; ++ni)
                    atomicAdd(&dst[ni * 16 + cn], wgt * acc[mi][ni][r]);
            }
        }
    }
}

// ---------------- fallback (only if ws too small): slow but correct ----------------
__global__ __launch_bounds__(256)
void k_fallback(const float* __restrict__ x, const int* __restrict__ eidx,
                const float* __restrict__ ew, const float* __restrict__ w1,
                const float* __restrict__ w2, const float* __restrict__ w3,
                float* __restrict__ out)
{
    __shared__ float xs[DM];
    __shared__ float hs[DF];
    const int pair = blockIdx.x;
    const int t = pair >> 1;
    const int e = eidx[pair] & 7;
    const float wgt = ew[pair];
    const int tid = threadIdx.x;
    for (int i = tid; i < DM; i += 256) xs[i] = x[(size_t)t * DM + i];
    __syncthreads();
    for (int f = tid; f < DF; f += 256) {
        const float* c1 = w1 + (size_t)e * DM * DF + f;
        const float* c2 = w2 + (size_t)e * DM * DF + f;
        float g = 0.f, v = 0.f;
        for (int d = 0; d < DM; ++d) {
            float xv = xs[d];
            g += xv * c1[(size_t)d * DF];
            v += xv * c2[(size_t)d * DF];
        }
        hs[f] = (g * v) / (1.f + __expf(-g));
    }
    __syncthreads();
    for (int d = tid; d < DM; d += 256) {
        const float* c3 = w3 + (size_t)e * DF * DM + d;
        float o = 0.f;
        for (int f = 0; f < DF; ++f) o += hs[f] * c3[(size_t)f * DM];
        atomicAdd(&out[(size_t)t * DM + d], wgt * o);
    }
}

extern "C" void kernel_launch(void* const* d_in, const int* in_sizes, int n_in,
                              void* d_out, int out_size, void* d_ws, size_t ws_size,
                              hipStream_t stream)
{
    const float* x  = (const float*)d_in[0];
    const int*   ei = (const int*)  d_in[1];
    const float* ew = (const float*)d_in[2];
    const float* w1 = (const float*)d_in[3];
    const float* w2 = (const float*)d_in[4];
    const float* w3 = (const float*)d_in[5];
    float* out = (float*)d_out;

    (void)hipMemsetAsync(d_out, 0, (size_t)out_size * sizeof(float), stream);

    const size_t need = 65536 + (size_t)NPAIR * DF * sizeof(unsigned short);
    if (ws_size < need) {
        k_fallback<<<NPAIR, 256, 0, stream>>>(x, ei, ew, w1, w2, w3, out);
        return;
    }

    int* meta = (int*)d_ws;
    int* rows = meta + 64;
    unsigned short* H = (unsigned short*)((char*)d_ws + 65536);

    (void)hipMemsetAsync(d_ws, 0, 64, stream);  // counts + cursors
    k_count  <<<NPAIR / 256, 256, 0, stream>>>(ei, meta);
    k_scan   <<<1, 64, 0, stream>>>(meta);
    k_scatter<<<NPAIR / 256, 256, 0, stream>>>(ei, meta, rows);
    k_gemm1  <<<dim3(DF / BN, NPAIR / BM + NEXP), 256, 0, stream>>>(x, w1, w2, meta, rows, H);
    k_gemm2  <<<dim3(DM / BN, NPAIR / BM + NEXP), 256, 0, stream>>>(H, w3, meta, rows, ew, out);
}

// Round 4
// 490.329 us; speedup vs baseline: 1.2278x; 1.2278x over previous
//
#include <hip/hip_runtime.h>
#include <hip/hip_bf16.h>

#define N_TOK   4096
#define DM      1024
#define DF      2048
#define NEXP    8
#define NPAIR   (N_TOK * 2)
#define BM      128
#define BN      128
#define BK      32
#define LDK     40      // fallback path only

typedef __attribute__((ext_vector_type(8))) short bf16x8;
typedef __attribute__((ext_vector_type(4))) float f32x4;

__device__ __forceinline__ unsigned short to_bf16(float f) {
    unsigned u = __builtin_bit_cast(unsigned, f);
    unsigned r = (u + 0x7FFFu + ((u >> 16) & 1u)) >> 16;
    return (unsigned short)r;
}
__device__ __forceinline__ unsigned pk_bf16(float a, float b) {
    return (unsigned)to_bf16(a) | ((unsigned)to_bf16(b) << 16);
}
// async global->LDS, 16B per lane; LDS dest = wave-uniform base + lane*16
__device__ __forceinline__ void gld16(const unsigned short* g, unsigned short* l) {
    __builtin_amdgcn_global_load_lds(
        (const __attribute__((address_space(1))) unsigned int*)(g),
        (__attribute__((address_space(3))) unsigned int*)(l), 16, 0, 0);
}

// ---------------- sort pairs by expert ----------------
// meta: [0..8) counts, [8..16) cursors, [16..25) rowOff, [25..34) mtOff, [34] totalMT
__global__ void k_count(const int* __restrict__ eidx, int* __restrict__ meta) {
    int i = blockIdx.x * 256 + threadIdx.x;
    if (i < NPAIR) atomicAdd(&meta[eidx[i] & 7], 1);
}
__global__ void k_scan(int* __restrict__ meta) {
    if (threadIdx.x == 0) {
        int off = 0, mt = 0;
        for (int e = 0; e < NEXP; ++e) {
            meta[16 + e] = off; meta[25 + e] = mt;
            int c = meta[e];
            off += c; mt += (c + BM - 1) / BM;
        }
        meta[16 + NEXP] = off; meta[25 + NEXP] = mt; meta[34] = mt;
    }
}
__global__ void k_scatter(const int* __restrict__ eidx, int* __restrict__ meta,
                          int* __restrict__ rows) {
    int i = blockIdx.x * 256 + threadIdx.x;
    if (i < NPAIR) {
        int e = eidx[i] & 7;
        int p = meta[16 + e] + atomicAdd(&meta[8 + e], 1);
        rows[p] = i;
    }
}

// ---------------- pre-passes: dtype conversion + weight transpose ----------------
__global__ __launch_bounds__(256)
void k_cvt_x(const float* __restrict__ x, unsigned short* __restrict__ xb) {
    int i = (blockIdx.x * 256 + threadIdx.x) * 8;
    float4 v0 = *(const float4*)(x + i);
    float4 v1 = *(const float4*)(x + i + 4);
    uint4 w;
    w.x = pk_bf16(v0.x, v0.y); w.y = pk_bf16(v0.z, v0.w);
    w.z = pk_bf16(v1.x, v1.y); w.w = pk_bf16(v1.z, v1.w);
    *(uint4*)(xb + i) = w;
}

// src [E][K][F] fp32 -> dst [E][F][K] bf16.  grid = (F/64, K/64, E), block 256
// LDS tile layout: tile[k*80 + f]  (k-major, 80-short row pad)
__global__ __launch_bounds__(256)
void k_transpose(const float* __restrict__ src, unsigned short* __restrict__ dst,
                 int K, int F) {
    __shared__ __align__(16) unsigned short tile[64 * 80];
    const int e  = blockIdx.z;
    const int k0 = blockIdx.y * 64;
    const int f0 = blockIdx.x * 64;
    const int t  = threadIdx.x;
    const float* s = src + (size_t)e * K * F;
    unsigned short* d = dst + (size_t)e * K * F;
    const int fi = t & 63;
    const int kg = t >> 6;
    #pragma unroll
    for (int i = 0; i < 16; ++i) {
        int k = kg * 16 + i;
        tile[k * 80 + fi] = to_bf16(s[(size_t)(k0 + k) * F + f0 + fi]);
    }
    __syncthreads();
    // store: fixed f, gather k-strided from tile, write contiguous 16B
    const int kc = (t & 7) * 8;
    const int fo = t >> 3;
    #pragma unroll
    for (int j = 0; j < 2; ++j) {
        int f = fo + j * 32;
        unsigned short v[8];
        #pragma unroll
        for (int i = 0; i < 8; ++i) v[i] = tile[(kc + i) * 80 + f];
        uint4 w;
        w.x = (unsigned)v[0] | ((unsigned)v[1] << 16);
        w.y = (unsigned)v[2] | ((unsigned)v[3] << 16);
        w.z = (unsigned)v[4] | ((unsigned)v[5] << 16);
        w.w = (unsigned)v[6] | ((unsigned)v[7] << 16);
        *(uint4*)&d[(size_t)(f0 + f) * K + k0 + kc] = w;
    }
}

// ---------------- bf16 GEMM1: H = silu(X W1) * (X W2) ----------------
__global__ __launch_bounds__(256, 2)
void k_gemm1_bf(const unsigned short* __restrict__ xb,
                const unsigned short* __restrict__ w1t,  // [E][F][K=DM]
                const unsigned short* __restrict__ w2t,
                const int* __restrict__ meta,
                const int* __restrict__ rows,
                unsigned short* __restrict__ H)
{
    __shared__ __align__(16) unsigned short As [BM * BK];
    __shared__ __align__(16) unsigned short B1s[BN * BK];
    __shared__ __align__(16) unsigned short B2s[BN * BK];
    __shared__ int s_tok[BM];

    const int mt = blockIdx.y;
    if (mt >= meta[34]) return;
    int e = 0;
    #pragma unroll
    for (int i = 0; i < NEXP - 1; ++i) if (mt >= meta[25 + i + 1]) e = i + 1;
    const int rowEnd = meta[16 + e + 1];
    const int row0   = meta[16 + e] + (mt - meta[25 + e]) * BM;
    const int f0     = blockIdx.x * BN;
    const int tid    = threadIdx.x;

    if (tid < BM) {
        int gr = row0 + tid;
        s_tok[tid] = (gr < rowEnd) ? (rows[gr] >> 1) : 0;
    }
    __syncthreads();

    const int lane = tid & 63;
    const int wave = tid >> 6;
    // staging: lane owns row wave*32 + lane/4 (+16 for 2nd call), k-elems (lane&3)*8..+8
    const int r0 = wave * 32 + (lane >> 2);
    const int r1 = r0 + 16;
    const int kb = (lane & 3) * 8;
    const unsigned short* a_src0 = xb + (size_t)s_tok[r0] * DM + kb;
    const unsigned short* a_src1 = xb + (size_t)s_tok[r1] * DM + kb;
    const size_t wb = (size_t)e * DM * DF;
    const unsigned short* b1_src0 = w1t + wb + (size_t)(f0 + r0) * DM + kb;
    const unsigned short* b1_src1 = w1t + wb + (size_t)(f0 + r1) * DM + kb;
    const unsigned short* b2_src0 = w2t + wb + (size_t)(f0 + r0) * DM + kb;
    const unsigned short* b2_src1 = w2t + wb + (size_t)(f0 + r1) * DM + kb;
    unsigned short* As0  = &As [wave * 1024];
    unsigned short* As1  = &As [wave * 1024 + 512];
    unsigned short* B1s0 = &B1s[wave * 1024];
    unsigned short* B1s1 = &B1s[wave * 1024 + 512];
    unsigned short* B2s0 = &B2s[wave * 1024];
    unsigned short* B2s1 = &B2s[wave * 1024 + 512];

    f32x4 accg[4][4], accv[4][4];
    #pragma unroll
    for (int i = 0; i < 4; ++i)
        #pragma unroll
        for (int j = 0; j < 4; ++j) { accg[i][j] = (f32x4)0.f; accv[i][j] = (f32x4)0.f; }

    const int wm = (wave >> 1) * 64;
    const int wn = (wave & 1) * 64;
    const int am = lane & 15;
    const int ak = (lane >> 4) * 8;

    for (int k0 = 0; k0 < DM; k0 += BK) {
        gld16(a_src0 + k0, As0);
        gld16(a_src1 + k0, As1);
        gld16(b1_src0 + k0, B1s0);
        gld16(b1_src1 + k0, B1s1);
        gld16(b2_src0 + k0, B2s0);
        gld16(b2_src1 + k0, B2s1);
        __syncthreads();

        bf16x8 a[4], b1[4], b2[4];
        #pragma unroll
        for (int mi = 0; mi < 4; ++mi) a[mi] = *(const bf16x8*)&As[(wm + mi * 16 + am) * BK + ak];
        #pragma unroll
        for (int ni = 0; ni < 4; ++ni) {
            b1[ni] = *(const bf16x8*)&B1s[(wn + ni * 16 + am) * BK + ak];
            b2[ni] = *(const bf16x8*)&B2s[(wn + ni * 16 + am) * BK + ak];
        }
        #pragma unroll
        for (int mi = 0; mi < 4; ++mi)
            #pragma unroll
            for (int ni = 0; ni < 4; ++ni) {
                accg[mi][ni] = __builtin_amdgcn_mfma_f32_16x16x32_bf16(a[mi], b1[ni], accg[mi][ni], 0, 0, 0);
                accv[mi][ni] = __builtin_amdgcn_mfma_f32_16x16x32_bf16(a[mi], b2[ni], accv[mi][ni], 0, 0, 0);
            }
        __syncthreads();
    }

    const int cn = lane & 15;
    const int cq = (lane >> 4) * 4;
    #pragma unroll
    for (int mi = 0; mi < 4; ++mi) {
        #pragma unroll
        for (int r = 0; r < 4; ++r) {
            const int row = wm + mi * 16 + cq + r;
            const int gr  = row0 + row;
            if (gr < rowEnd) {
                unsigned short* dst = H + (size_t)gr * DF + f0 + wn;
                #pragma unroll
                for (int ni = 0; ni < 4; ++ni) {
                    float g = accg[mi][ni][r];
                    float v = accv[mi][ni][r];
                    float h = (g * v) / (1.f + __expf(-g));
                    dst[ni * 16 + cn] = to_bf16(h);
                }
            }
        }
    }
}

// ---------------- bf16 GEMM2: out[tok] += w * (H @ W3) ----------------
__global__ __launch_bounds__(256, 2)
void k_gemm2_bf(const unsigned short* __restrict__ H,
                const unsigned short* __restrict__ w3t,  // [E][D=DM][K=DF]
                const int* __restrict__ meta,
                const int* __restrict__ rows,
                const float* __restrict__ ew,
                float* __restrict__ out)
{
    __shared__ __align__(16) unsigned short As[BM * BK];
    __shared__ __align__(16) unsigned short Bs[BN * BK];
    __shared__ int   s_tok[BM];
    __shared__ float s_w[BM];

    const int mt = blockIdx.y;
    if (mt >= meta[34]) return;
    int e = 0;
    #pragma unroll
    for (int i = 0; i < NEXP - 1; ++i) if (mt >= meta[25 + i + 1]) e = i + 1;
    const int rowEnd = meta[16 + e + 1];
    const int row0   = meta[16 + e] + (mt - meta[25 + e]) * BM;
    const int d0     = blockIdx.x * BN;
    const int tid    = threadIdx.x;

    if (tid < BM) {
        int gr = row0 + tid;
        if (gr < rowEnd) { int pr = rows[gr]; s_tok[tid] = pr >> 1; s_w[tid] = ew[pr]; }
        else             { s_tok[tid] = 0;    s_w[tid] = 0.f; }
    }
    __syncthreads();

    const int lane = tid & 63;
    const int wave = tid >> 6;
    const int r0 = wave * 32 + (lane >> 2);
    const int r1 = r0 + 16;
    const int kb = (lane & 3) * 8;
    int gr0 = row0 + r0; if (gr0 > NPAIR - 1) gr0 = NPAIR - 1;
    int gr1 = row0 + r1; if (gr1 > NPAIR - 1) gr1 = NPAIR - 1;
    const unsigned short* a_src0 = H + (size_t)gr0 * DF + kb;
    const unsigned short* a_src1 = H + (size_t)gr1 * DF + kb;
    const size_t wb = (size_t)e * DM * DF;
    const unsigned short* b_src0 = w3t + wb + (size_t)(d0 + r0) * DF + kb;
    const unsigned short* b_src1 = w3t + wb + (size_t)(d0 + r1) * DF + kb;
    unsigned short* As0 = &As[wave * 1024];
    unsigned short* As1 = &As[wave * 1024 + 512];
    unsigned short* Bs0 = &Bs[wave * 1024];
    unsigned short* Bs1 = &Bs[wave * 1024 + 512];

    f32x4 acc[4][4];
    #pragma unroll
    for (int i = 0; i < 4; ++i)
        #pragma unroll
        for (int j = 0; j < 4; ++j) acc[i][j] = (f32x4)0.f;

    const int wm = (wave >> 1) * 64;
    const int wn = (wave & 1) * 64;
    const int am = lane & 15;
    const int ak = (lane >> 4) * 8;

    for (int k0 = 0; k0 < DF; k0 += BK) {
        gld16(a_src0 + k0, As0);
        gld16(a_src1 + k0, As1);
        gld16(b_src0 + k0, Bs0);
        gld16(b_src1 + k0, Bs1);
        __syncthreads();

        bf16x8 a[4], b[4];
        #pragma unroll
        for (int mi = 0; mi < 4; ++mi) a[mi] = *(const bf16x8*)&As[(wm + mi * 16 + am) * BK + ak];
        #pragma unroll
        for (int ni = 0; ni < 4; ++ni) b[ni] = *(const bf16x8*)&Bs[(wn + ni * 16 + am) * BK + ak];
        #pragma unroll
        for (int mi = 0; mi < 4; ++mi)
            #pragma unroll
            for (int ni = 0; ni < 4; ++ni)
                acc[mi][ni] = __builtin_amdgcn_mfma_f32_16x16x32_bf16(a[mi], b[ni], acc[mi][ni], 0, 0, 0);
        __syncthreads();
    }

    const int cn = lane & 15;
    const int cq = (lane >> 4) * 4;
    #pragma unroll
    for (int mi = 0; mi < 4; ++mi) {
        #pragma unroll
        for (int r = 0; r < 4; ++r) {
            const int row = wm + mi * 16 + cq + r;
            const int gr  = row0 + row;
            if (gr < rowEnd) {
                const int   tok = s_tok[row];
                const float wgt = s_w[row];
                float* dst = out + (size_t)tok * DM + d0 + wn;
                #pragma unroll
                for (int ni = 0; ni < 4; ++ni)
                    atomicAdd(&dst[ni * 16 + cn], wgt * acc[mi][ni][r]);
            }
        }
    }
}

// ================= fallback path (round-2 kernels, used if ws too small) =================
__global__ __launch_bounds__(256, 2)
void k_gemm1(const float* __restrict__ x, const float* __restrict__ w1,
             const float* __restrict__ w2, const int* __restrict__ meta,
             const int* __restrict__ rows, unsigned short* __restrict__ H)
{
    __shared__ unsigned short As[BM][LDK];
    __shared__ unsigned short B1s[BN][LDK];
    __shared__ unsigned short B2s[BN][LDK];
    __shared__ int s_tok[BM];
    const int mt = blockIdx.y;
    if (mt >= meta[34]) return;
    int e = 0;
    #pragma unroll
    for (int i = 0; i < NEXP - 1; ++i) if (mt >= meta[25 + i + 1]) e = i + 1;
    const int rowEnd = meta[16 + e + 1];
    const int row0   = meta[16 + e] + (mt - meta[25 + e]) * BM;
    const int f0     = blockIdx.x * BN;
    const int tid    = threadIdx.x;
    if (tid < BM) {
        int gr = row0 + tid;
        s_tok[tid] = (gr < rowEnd) ? (rows[gr] >> 1) : -1;
    }
    __syncthreads();
    const int ar = tid >> 1;
    const int ah = (tid & 1) * 16;
    const int a_tok = s_tok[ar];
    const float* a_src = x + (size_t)(a_tok < 0 ? 0 : a_tok) * DM + ah;
    const int bn_ = tid & 127;
    const int bk_ = (tid >> 7) * 16;
    const float* b1_src = w1 + (size_t)e * DM * DF + (size_t)bk_ * DF + f0 + bn_;
    const float* b2_src = w2 + (size_t)e * DM * DF + (size_t)bk_ * DF + f0 + bn_;
    f32x4 accg[4][4], accv[4][4];
    #pragma unroll
    for (int i = 0; i < 4; ++i)
        #pragma unroll
        for (int j = 0; j < 4; ++j) { accg[i][j] = (f32x4)0.f; accv[i][j] = (f32x4)0.f; }
    const int lane = tid & 63;
    const int wave = tid >> 6;
    const int wm = (wave >> 1) * 64;
    const int wn = (wave & 1) * 64;
    const int am = lane & 15;
    const int ak = (lane >> 4) * 8;
    for (int k0 = 0; k0 < DM; k0 += BK) {
        {
            const float* p = a_src + k0;
            #pragma unroll
            for (int jj = 0; jj < 4; ++jj) {
                float4 v;
                if (a_tok < 0) { v.x = v.y = v.z = v.w = 0.f; }
                else           { v = *(const float4*)(p + jj * 4); }
                uint2 w;
                w.x = pk_bf16(v.x, v.y); w.y = pk_bf16(v.z, v.w);
                *(uint2*)&As[ar][ah + jj * 4] = w;
            }
        }
        {
            const float* p1 = b1_src + (size_t)k0 * DF;
            const float* p2 = b2_src + (size_t)k0 * DF;
            #pragma unroll
            for (int c = 0; c < 2; ++c) {
                float v[8];
                #pragma unroll
                for (int j = 0; j < 8; ++j) v[j] = p1[(size_t)(c * 8 + j) * DF];
                uint4 w;
                w.x = pk_bf16(v[0], v[1]); w.y = pk_bf16(v[2], v[3]);
                w.z = pk_bf16(v[4], v[5]); w.w = pk_bf16(v[6], v[7]);
                *(uint4*)&B1s[bn_][bk_ + c * 8] = w;
            }
            #pragma unroll
            for (int c = 0; c < 2; ++c) {
                float v[8];
                #pragma unroll
                for (int j = 0; j < 8; ++j) v[j] = p2[(size_t)(c * 8 + j) * DF];
                uint4 w;
                w.x = pk_bf16(v[0], v[1]); w.y = pk_bf16(v[2], v[3]);
                w.z = pk_bf16(v[4], v[5]); w.w = pk_bf16(v[6], v[7]);
                *(uint4*)&B2s[bn_][bk_ + c * 8] = w;
            }
        }
        __syncthreads();
        bf16x8 a[4], b1[4], b2[4];
        #pragma unroll
        for (int mi = 0; mi < 4; ++mi) a[mi] = *(const bf16x8*)&As[wm + mi * 16 + am][ak];
        #pragma unroll
        for (int ni = 0; ni < 4; ++ni) {
            b1[ni] = *(const bf16x8*)&B1s[wn + ni * 16 + am][ak];
            b2[ni] = *(const bf16x8*)&B2s[wn + ni * 16 + am][ak];
        }
        #pragma unroll
        for (int mi = 0; mi < 4; ++mi)
            #pragma unroll
            for (int ni = 0; ni < 4; ++ni) {
                accg[mi][ni] = __builtin_amdgcn_mfma_f32_16x16x32_bf16(a[mi], b1[ni], accg[mi][ni], 0, 0, 0);
                accv[mi][ni] = __builtin_amdgcn_mfma_f32_16x16x32_bf16(a[mi], b2[ni], accv[mi][ni], 0, 0, 0);
            }
        __syncthreads();
    }
    const int cn = lane & 15;
    const int cq = (lane >> 4) * 4;
    #pragma unroll
    for (int mi = 0; mi < 4; ++mi) {
        #pragma unroll
        for (int r = 0; r < 4; ++r) {
            const int row = wm + mi * 16 + cq + r;
            const int gr  = row0 + row;
            if (gr < rowEnd) {
                unsigned short* dst = H + (size_t)gr * DF + f0 + wn;
                #pragma unroll
                for (int ni = 0; ni < 4; ++ni) {
                    float g = accg[mi][ni][r];
                    float v = accv[mi][ni][r];
                    float h = (g * v) / (1.f + __expf(-g));
                    dst[ni * 16 + cn] = to_bf16(h);
                }
            }
        }
    }
}

__global__ __launch_bounds__(256, 2)
void k_gemm2(const unsigned short* __restrict__ H, const float* __restrict__ w3,
             const int* __restrict__ meta, const int* __restrict__ rows,
             const float* __restrict__ ew, float* __restrict__ out)
{
    __shared__ unsigned short As[BM][LDK];
    __shared__ unsigned short Bs[BN][LDK];
    __shared__ int   s_tok[BM];
    __shared__ float s_w[BM];
    const int mt = blockIdx.y;
    if (mt >= meta[34]) return;
    int e = 0;
    #pragma unroll
    for (int i = 0; i < NEXP - 1; ++i) if (mt >= meta[25 + i + 1]) e = i + 1;
    const int rowEnd = meta[16 + e + 1];
    const int row0   = meta[16 + e] + (mt - meta[25 + e]) * BM;
    const int d0     = blockIdx.x * BN;
    const int tid    = threadIdx.x;
    if (tid < BM) {
        int gr = row0 + tid;
        if (gr < rowEnd) { int pr = rows[gr]; s_tok[tid] = pr >> 1; s_w[tid] = ew[pr]; }
        else             { s_tok[tid] = 0;    s_w[tid] = 0.f; }
    }
    __syncthreads();
    const int ar = tid >> 1;
    const int ah = (tid & 1) * 16;
    int a_row = row0 + ar; if (a_row >= NPAIR) a_row = NPAIR - 1;
    const unsigned short* a_src = H + (size_t)a_row * DF + ah;
    const int bn_ = tid & 127;
    const int bk_ = (tid >> 7) * 16;
    const float* b_src = w3 + (size_t)e * DF * DM + (size_t)bk_ * DM + d0 + bn_;
    f32x4 acc[4][4];
    #pragma unroll
    for (int i = 0; i < 4; ++i)
        #pragma unroll
        for (int j = 0; j < 4; ++j) acc[i][j] = (f32x4)0.f;
    const int lane = tid & 63;
    const int wave = tid >> 6;
    const int wm = (wave >> 1) * 64;
    const int wn = (wave & 1) * 64;
    const int am = lane & 15;
    const int ak = (lane >> 4) * 8;
    for (int k0 = 0; k0 < DF; k0 += BK) {
        *(uint4*)&As[ar][ah]     = *(const uint4*)(a_src + k0);
        *(uint4*)&As[ar][ah + 8] = *(const uint4*)(a_src + k0 + 8);
        {
            const float* p = b_src + (size_t)k0 * DM;
            #pragma unroll
            for (int c = 0; c < 2; ++c) {
                float v[8];
                #pragma unroll
                for (int j = 0; j < 8; ++j) v[j] = p[(size_t)(c * 8 + j) * DM];
                uint4 w;
                w.x = pk_bf16(v[0], v[1]); w.y = pk_bf16(v[2], v[3]);
                w.z = pk_bf16(v[4], v[5]); w.w = pk_bf16(v[6], v[7]);
                *(uint4*)&Bs[bn_][bk_ + c * 8] = w;
            }
        }
        __syncthreads();
        bf16x8 a[4], b[4];
        #pragma unroll
        for (int mi = 0; mi < 4; ++mi) a[mi] = *(const bf16x8*)&As[wm + mi * 16 + am][ak];
        #pragma unroll
        for (int ni = 0; ni < 4; ++ni) b[ni] = *(const bf16x8*)&Bs[wn + ni * 16 + am][ak];
        #pragma unroll
        for (int mi = 0; mi < 4; ++mi)
            #pragma unroll
            for (int ni = 0; ni < 4; ++ni)
                acc[mi][ni] = __builtin_amdgcn_mfma_f32_16x16x32_bf16(a[mi], b[ni], acc[mi][ni], 0, 0, 0);
        __syncthreads();
    }
    const int cn = lane & 15;
    const int cq = (lane >> 4) * 4;
    #pragma unroll
    for (int mi = 0; mi < 4; ++mi) {
        #pragma unroll
        for (int r = 0; r < 4; ++r) {
            const int row = wm + mi * 16 + cq + r;
            const int gr  = row0 + row;
            if (gr < rowEnd) {
                const int   tok = s_tok[row];
                const float wgt = s_w[row];
                float* dst = out + (size_t)tok * DM + d0 + wn;
                #pragma unroll
                for (int ni = 0; ni < 4; ++ni)
                    atomicAdd(&dst[ni * 16 + cn], wgt * acc[mi][ni][r]);
            }
        }
    }
}

__global__ __launch_bounds__(256)
void k_fallback(const float* __restrict__ x, const int* __restrict__ eidx,
                const float* __restrict__ ew, const float* __restrict__ w1,
                const float* __restrict__ w2, const float* __restrict__ w3,
                float* __restrict__ out)
{
    __shared__ float xs[DM];
    __shared__ float hs[DF];
    const int pair = blockIdx.x;
    const int t = pair >> 1;
    const int e = eidx[pair] & 7;
    const float wgt = ew[pair];
    const int tid = threadIdx.x;
    for (int i = tid; i < DM; i += 256) xs[i] = x[(size_t)t * DM + i];
    __syncthreads();
    for (int f = tid; f < DF; f += 256) {
        const float* c1 = w1 + (size_t)e * DM * DF + f;
        const float* c2 = w2 + (size_t)e * DM * DF + f;
        float g = 0.f, v = 0.f;
        for (int d = 0; d < DM; ++d) {
            float xv = xs[d];
            g += xv * c1[(size_t)d * DF];
            v += xv * c2[(size_t)d * DF];
        }
        hs[f] = (g * v) / (1.f + __expf(-g));
    }
    __syncthreads();
    for (int d = tid; d < DM; d += 256) {
        const float* c3 = w3 + (size_t)e * DF * DM + d;
        float o = 0.f;
        for (int f = 0; f < DF; ++f) o += hs[f] * c3[(size_t)f * DM];
        atomicAdd(&out[(size_t)t * DM + d], wgt * o);
    }
}

extern "C" void kernel_launch(void* const* d_in, const int* in_sizes, int n_in,
                              void* d_out, int out_size, void* d_ws, size_t ws_size,
                              hipStream_t stream)
{
    const float* x  = (const float*)d_in[0];
    const int*   ei = (const int*)  d_in[1];
    const float* ew = (const float*)d_in[2];
    const float* w1 = (const float*)d_in[3];
    const float* w2 = (const float*)d_in[4];
    const float* w3 = (const float*)d_in[5];
    float* out = (float*)d_out;

    (void)hipMemsetAsync(d_out, 0, (size_t)out_size * sizeof(float), stream);

    const size_t SZ_H  = (size_t)NPAIR * DF * 2;     // 32 MB
    const size_t SZ_XB = (size_t)N_TOK * DM * 2;     // 8 MB
    const size_t SZ_W  = (size_t)NEXP * DM * DF * 2; // 32 MB each
    const size_t OFF_H  = 65536;
    const size_t OFF_XB = OFF_H + SZ_H;
    const size_t OFF_W1 = OFF_XB + SZ_XB;
    const size_t OFF_W2 = OFF_W1 + SZ_W;
    const size_t OFF_W3 = OFF_W2 + SZ_W;
    const size_t NEED_BIG   = OFF_W3 + SZ_W;
    const size_t NEED_SMALL = OFF_H + SZ_H;

    if (ws_size < NEED_SMALL) {
        k_fallback<<<NPAIR, 256, 0, stream>>>(x, ei, ew, w1, w2, w3, out);
        return;
    }

    int* meta = (int*)d_ws;
    int* rows = meta + 64;
    unsigned short* H = (unsigned short*)((char*)d_ws + OFF_H);

    (void)hipMemsetAsync(d_ws, 0, 64, stream);
    k_count  <<<NPAIR / 256, 256, 0, stream>>>(ei, meta);
    k_scan   <<<1, 64, 0, stream>>>(meta);
    k_scatter<<<NPAIR / 256, 256, 0, stream>>>(ei, meta, rows);

    if (ws_size >= NEED_BIG) {
        unsigned short* xb  = (unsigned short*)((char*)d_ws + OFF_XB);
        unsigned short* w1t = (unsigned short*)((char*)d_ws + OFF_W1);
        unsigned short* w2t = (unsigned short*)((char*)d_ws + OFF_W2);
        unsigned short* w3t = (unsigned short*)((char*)d_ws + OFF_W3);
        k_cvt_x<<<(N_TOK * DM) / 2048, 256, 0, stream>>>(x, xb);
        k_transpose<<<dim3(DF / 64, DM / 64, NEXP), 256, 0, stream>>>(w1, w1t, DM, DF);
        k_transpose<<<dim3(DF / 64, DM / 64, NEXP), 256, 0, stream>>>(w2, w2t, DM, DF);
        k_transpose<<<dim3(DM / 64, DF / 64, NEXP), 256, 0, stream>>>(w3, w3t, DF, DM);
        k_gemm1_bf<<<dim3(DF / BN, NPAIR / BM + NEXP), 256, 0, stream>>>(xb, w1t, w2t, meta, rows, H);
        k_gemm2_bf<<<dim3(DM / BN, NPAIR / BM + NEXP), 256, 0, stream>>>(H, w3t, meta, rows, ew, out);
    } else {
        k_gemm1<<<dim3(DF / BN, NPAIR / BM + NEXP), 256, 0, stream>>>(x, w1, w2, meta, rows, H);
        k_gemm2<<<dim3(DM / BN, NPAIR / BM + NEXP), 256, 0, stream>>>(H, w3, meta, rows, ew, out);
    }
}